// Round 18
// baseline (204.923 us; speedup 1.0000x reference)
//
#include <hip/hip_runtime.h>
#include <hip/hip_bf16.h>

// Color_Attention: transposed (channel) attention.
//   gram2_k (fused): 768 thr / 12 waves, 80KB LDS -> 2 blocks/CU.
//   grid (64, 8) = 512 blocks: two resident blocks per CU overlap their
//   stage/pack/MFMA phases (partials live in d_out scratch so the grid no
//   longer depends on ws_size). Stages fp32 [I;C] 384x16-col chunk-pairs
//   via global_load_lds (2 slots), packs to bf16 (80B rows), MFMA 32x32x16
//   on Z*Z^T upper triangle: 6 pairs (r,11-r) x 13 tiles split 7/6 across
//   two waves (acc 112/96 VGPRs; no launch_bounds beyond 768 - R14 lesson).
//   Sync via __syncthreads() only (R13 raw-barrier raced).
//   reduce_k (NP=64) sums bf16 partials -> fp32 G (both triangles).
//   A_pre = Wq*G_ci*Wk^T ; nq = diag(Wq*G_cc*Wq^T); nk = diag(Wk*G_ii*Wk^T)
//   attn = softmax over head-diagonal 24x24 blocks of A_pre/(nq*nk)
//   P = Wo * blockdiag(attn) * Wv ; out = P @ input

typedef __attribute__((ext_vector_type(4))) float f32x4;
typedef __attribute__((ext_vector_type(16))) float f32x16;
typedef __attribute__((ext_vector_type(8))) short short8;

#define MFMA16(a, b, c) __builtin_amdgcn_mfma_f32_16x16x32_bf16((a), (b), (c), 0, 0, 0)
#define MFMA32(a, b, c) __builtin_amdgcn_mfma_f32_32x32x16_bf16((a), (b), (c), 0, 0, 0)

__device__ __forceinline__ unsigned int pack_rne(float a, float b) {
  unsigned int ua = __float_as_uint(a), ub = __float_as_uint(b);
  ua += 0x7fffu + ((ua >> 16) & 1u);
  ub += 0x7fffu + ((ub >> 16) & 1u);
  return (ua >> 16) | (ub & 0xffff0000u);
}
__device__ __forceinline__ unsigned short bf16u_rne(float x) {
  unsigned int u = __float_as_uint(x);
  u += 0x7fffu + ((u >> 16) & 1u);
  return (unsigned short)(u >> 16);
}
union S8U { short8 s; unsigned int u[4]; };
__device__ __forceinline__ short8 load_cvt8(const float* p) {
  f32x4 x = *(const f32x4*)p;
  f32x4 y = *(const f32x4*)(p + 4);
  S8U r;
  r.u[0] = pack_rne(x[0], x[1]);
  r.u[1] = pack_rne(x[2], x[3]);
  r.u[2] = pack_rne(y[0], y[1]);
  r.u[3] = pack_rne(y[2], y[3]);
  return r.s;
}

#define HW 16384
#define CDIM 192
#define NB 8
#define GSZ (CDIM * CDIM)
#define NREC 78       // 32x32 upper-triangle tiles of the 384x384 gram
#define NPART 64      // partial sets; 512 blocks, 2 resident blocks/CU
#define NCP 8         // chunk-pairs (32 cols) per block: 64*8*32 = 16384
#define FSLOT 24576   // fp32 slot: 384 rows x 16 cols x 4B (64B/row)
#define FSKEW 64
#define BROW 80       // bf16 buffer row stride

// ---------------- Kernel 0: transpose Wv -> bf16 WvT ----------------
__global__ void k0_wvt(const float* __restrict__ Wv, unsigned short* __restrict__ WvT) {
  int idx = blockIdx.x * 256 + threadIdx.x;
  if (idx < CDIM * CDIM) {
    int j = idx / CDIM, cp = idx % CDIM;
    WvT[idx] = bf16u_rne(Wv[(size_t)cp * CDIM + j]);
  }
}

// ---------------- Kernel B (fused): gram Z*Z^T, fp32 direct staging ----------
// stage one 384x16-col fp32 chunk: 24 x 1KB gload_lds (2 per wave, 12 waves).
__device__ __forceinline__ void stageC(const float* __restrict__ ib,
                                       const float* __restrict__ cb, int col0,
                                       char* fdst, int wave, int lane) {
#pragma unroll
  for (int i = 0; i < 2; ++i) {
    const int g = wave * 2 + i;  // 0..23
    const int tensor = g >= 12;
    const int row = (g - (tensor ? 12 : 0)) * 16 + (lane >> 2);
    const float* T = tensor ? cb : ib;
    const float* gp = T + (size_t)row * HW + col0 + (lane & 3) * 4;
    __builtin_amdgcn_global_load_lds(
        (const __attribute__((address_space(1))) void*)gp,
        (__attribute__((address_space(3))) void*)(fdst + g * 1024), 16, 0, 0);
  }
}

// Pair p owns 32-row-tiles {p, 11-p}: 13 upper-triangle tiles
//   i=0..(11-p): rt=p, ct=p+i;  i=(12-p)..12: rt=11-p, ct=i-(12-p)+(11-p)
// HALF 0 -> i=0..6 (7 tiles), HALF 1 -> i=7..12 (6 tiles).
template <int P, int H>
__device__ __forceinline__ void pair_step32(const char* bb, f32x16* acc,
                                            int l31, int hi16, int kb) {
  constexpr int N0 = 12 - P;
  constexpr int I0 = H ? 7 : 0;
  constexpr int I1 = H ? 13 : 7;
  const short8 aP = *(const short8*)(bb + (P * 32 + l31) * BROW + hi16 + kb);
  short8 aQ = aP;
  if constexpr (I1 > N0)
    aQ = *(const short8*)(bb + ((11 - P) * 32 + l31) * BROW + hi16 + kb);
#pragma unroll
  for (int i = I0; i < I1; ++i) {
    const int ct = (i < N0) ? (P + i) : (i - N0 + 11 - P);
    const short8 bfr = *(const short8*)(bb + (ct * 32 + l31) * BROW + hi16 + kb);
    acc[i - I0] = MFMA32((i < N0) ? aP : aQ, bfr, acc[i - I0]);
  }
}

template <int P, int H>
__device__ __forceinline__ void pair_both(const char* bb, f32x16* acc,
                                          int l31, int hi16) {
  pair_step32<P, H>(bb, acc, l31, hi16, 0);
  pair_step32<P, H>(bb, acc, l31, hi16, 32);
}

__device__ __forceinline__ void pair_dispatch(int wave, const char* bb,
                                              f32x16* acc, int l31, int hi16) {
  switch (wave) {
    case 0: pair_both<0, 0>(bb, acc, l31, hi16); break;
    case 1: pair_both<0, 1>(bb, acc, l31, hi16); break;
    case 2: pair_both<1, 0>(bb, acc, l31, hi16); break;
    case 3: pair_both<1, 1>(bb, acc, l31, hi16); break;
    case 4: pair_both<2, 0>(bb, acc, l31, hi16); break;
    case 5: pair_both<2, 1>(bb, acc, l31, hi16); break;
    case 6: pair_both<3, 0>(bb, acc, l31, hi16); break;
    case 7: pair_both<3, 1>(bb, acc, l31, hi16); break;
    case 8: pair_both<4, 0>(bb, acc, l31, hi16); break;
    case 9: pair_both<4, 1>(bb, acc, l31, hi16); break;
    case 10: pair_both<5, 0>(bb, acc, l31, hi16); break;
    default: pair_both<5, 1>(bb, acc, l31, hi16); break;
  }
}

// grid (NPART, 8), 768 threads (12 waves). LDS ~80KB, 2 blocks/CU.
__global__ __launch_bounds__(768) void gram2_k(const float* __restrict__ input,
                                               const float* __restrict__ color,
                                               unsigned long long* __restrict__ part) {
  __shared__ __align__(16) char fbuf[2][FSLOT + FSKEW];
  __shared__ __align__(16) char bbuf[384 * BROW];
  const int tid = threadIdx.x, wave = tid >> 6, lane = tid & 63;
  const int l31 = lane & 31, hi16 = (lane >> 5) * 16;
  const int strip = blockIdx.x, b = blockIdx.y;
  const float* ib = input + (size_t)b * CDIM * HW;
  const float* cb = color + (size_t)b * CDIM * HW;
  const int ch0 = strip * NCP * 2;  // base chunk (16-col units)

  f32x16 acc[7];
#pragma unroll
  for (int s = 0; s < 7; ++s)
#pragma unroll
    for (int c = 0; c < 16; ++c) acc[s][c] = 0.f;

  stageC(ib, cb, (ch0 + 0) * 16, fbuf[0], wave, lane);
  stageC(ib, cb, (ch0 + 1) * 16, fbuf[1], wave, lane);

#pragma unroll 1
  for (int cp = 0; cp < NCP; ++cp) {
    __syncthreads();  // A: stage loads landed, prior bbuf reads done
    // ---- pack pair cp: 1536 units (32B fp32 -> 16B bf16), 2 per thread ----
    {
      const char* sA = fbuf[0];
      const char* sB = fbuf[1];
#pragma unroll
      for (int u0 = 0; u0 < 2; ++u0) {
        const int u = tid + u0 * 768;
        const int zr = u >> 2, sub = u & 3;
        const char* src = (sub < 2 ? sA : sB) + zr * 64 + (sub & 1) * 32;
        f32x4 x = *(const f32x4*)src;
        f32x4 y = *(const f32x4*)(src + 16);
        S8U pk;
        pk.u[0] = pack_rne(x[0], x[1]);
        pk.u[1] = pack_rne(x[2], x[3]);
        pk.u[2] = pack_rne(y[0], y[1]);
        pk.u[3] = pack_rne(y[2], y[3]);
        *(short8*)(bbuf + zr * BROW + sub * 16) = pk.s;
      }
    }
    __syncthreads();  // B: bbuf visible, fbuf free
    if (cp + 1 < NCP) {
      stageC(ib, cb, (ch0 + 2 * cp + 2) * 16, fbuf[0], wave, lane);
      stageC(ib, cb, (ch0 + 2 * cp + 3) * 16, fbuf[1], wave, lane);
    }
    pair_dispatch(wave, bbuf, acc, l31, hi16);
  }

  // ---- blocked flush, bf16: one contiguous 2KB record per 32x32 tile ----
  unsigned long long* pbase = part + (size_t)(b * NPART + strip) * NREC * 256;
  const int p = wave >> 1, H = wave & 1;
  const int Rbase = p * 13 + (H ? 7 : 0);
  const int NT = H ? 6 : 7;
#pragma unroll
  for (int s = 0; s < 7; ++s) {
    if (s < NT) {
#pragma unroll
      for (int j = 0; j < 4; ++j) {
        const unsigned long long pk =
            (unsigned long long)pack_rne(acc[s][4 * j], acc[s][4 * j + 1]) |
            ((unsigned long long)pack_rne(acc[s][4 * j + 2], acc[s][4 * j + 3]) << 32);
        pbase[((size_t)(Rbase + s) * 4 + j) * 64 + lane] = pk;
      }
    }
  }
}

// ---------------- reduce blocked bf16 partials -> fp32 G (both triangles) ---
// grid (78, NB), 256 threads: one 32x32 record per block, NP fully unrolled.
template <int NP>
__global__ __launch_bounds__(256) void reduce_k(const unsigned long long* __restrict__ part,
                                                float* __restrict__ G) {
  const int b = blockIdx.y, T = blockIdx.x;
  const int j = threadIdx.x >> 6, lane = threadIdx.x & 63;
  const unsigned long long* p0 =
      part + ((size_t)b * NP * NREC + T) * 256 + j * 64 + lane;
  float s0 = 0.f, s1 = 0.f, s2 = 0.f, s3 = 0.f;
#pragma unroll
  for (int s = 0; s < NP; ++s) {
    const unsigned long long v = p0[(size_t)s * NREC * 256];
    const unsigned int lo = (unsigned int)v, hi = (unsigned int)(v >> 32);
    s0 += __uint_as_float(lo << 16);
    s1 += __uint_as_float(lo & 0xffff0000u);
    s2 += __uint_as_float(hi << 16);
    s3 += __uint_as_float(hi & 0xffff0000u);
  }
  // decode record T -> 32-tile (rt, ct), rt <= ct
  const int p = T / 13, i = T % 13;
  const int N0 = 12 - p;
  const int rt = (i < N0) ? p : 11 - p;
  const int ct = (i < N0) ? p + i : i - N0 + 11 - p;
  const int hi5 = lane >> 5, col = lane & 31;
  const int zc = ct * 32 + col;
  const float sums[4] = {s0, s1, s2, s3};
#pragma unroll
  for (int m = 0; m < 4; ++m) {
    const int zr = rt * 32 + m + 8 * j + 4 * hi5;
    int type, gr, gc;
    if (zc < 192) { type = 2; gr = zr; gc = zc; }            // I*I^T
    else if (zr < 192) { type = 0; gr = zr; gc = zc - 192; } // I*C^T (full)
    else { type = 1; gr = zr - 192; gc = zc - 192; }         // C*C^T
    float* Gm = G + ((size_t)type * NB + b) * GSZ;
    Gm[(size_t)gr * CDIM + gc] = sums[m];
    if (type != 0 && rt != ct) Gm[(size_t)gc * CDIM + gr] = sums[m];
  }
}

// ---------------- Kernel 2a: A_pre (type0), nq (type1), nk (type2) ----------
__global__ __launch_bounds__(256) void k2a(const float* __restrict__ G,
                                           const float* __restrict__ Wq,
                                           const float* __restrict__ Wk,
                                           float* __restrict__ A_pre,
                                           float* __restrict__ nqk) {
  const int b = blockIdx.x, type = blockIdx.y;
  __shared__ __align__(16) unsigned short Hs[192][200];
  const int tid = threadIdx.x, wave = tid >> 6, lane = tid & 63;
  const int l15 = lane & 15, lg = lane >> 4, row0 = wave * 48;
  const float* W1 = (type == 2) ? Wk : Wq;
  const float* Gm = G + ((size_t)type * NB + b) * GSZ;

  f32x4 acc[3][12];
#pragma unroll
  for (int t = 0; t < 3; t++)
#pragma unroll
    for (int j = 0; j < 12; j++) acc[t][j] = (f32x4){0.f, 0.f, 0.f, 0.f};

  for (int ks = 0; ks < 192; ks += 32) {
    short8 afr[3];
#pragma unroll
    for (int t = 0; t < 3; t++)
      afr[t] = load_cvt8(W1 + (size_t)(row0 + t * 16 + l15) * CDIM + ks + lg * 8);
#pragma unroll
    for (int tj = 0; tj < 12; tj++) {
      short8 bfr = load_cvt8(Gm + (size_t)(tj * 16 + l15) * CDIM + ks + lg * 8);
#pragma unroll
      for (int t = 0; t < 3; t++) acc[t][tj] = MFMA16(afr[t], bfr, acc[t][tj]);
    }
  }
#pragma unroll
  for (int t = 0; t < 3; t++)
#pragma unroll
    for (int tj = 0; tj < 12; tj++)
#pragma unroll
      for (int r = 0; r < 4; r++)
        Hs[row0 + t * 16 + lg * 4 + r][tj * 16 + l15] = bf16u_rne(acc[t][tj][r]);
  __syncthreads();

  if (type == 0) {
    f32x4 a2[3][12];
#pragma unroll
    for (int t = 0; t < 3; t++)
#pragma unroll
      for (int j = 0; j < 12; j++) a2[t][j] = (f32x4){0.f, 0.f, 0.f, 0.f};
    for (int ks = 0; ks < 192; ks += 32) {
      short8 afr[3];
#pragma unroll
      for (int t = 0; t < 3; t++)
        afr[t] = *(const short8*)&Hs[row0 + t * 16 + l15][ks + lg * 8];
#pragma unroll
      for (int tj = 0; tj < 12; tj++) {
        short8 bfr = load_cvt8(Wk + (size_t)(tj * 16 + l15) * CDIM + ks + lg * 8);
#pragma unroll
        for (int t = 0; t < 3; t++) a2[t][tj] = MFMA16(afr[t], bfr, a2[t][tj]);
      }
    }
    float* Ab = A_pre + (size_t)b * GSZ;
#pragma unroll
    for (int t = 0; t < 3; t++)
#pragma unroll
      for (int tj = 0; tj < 12; tj++)
#pragma unroll
        for (int r = 0; r < 4; r++)
          Ab[(size_t)(row0 + t * 16 + lg * 4 + r) * CDIM + tj * 16 + l15] = a2[t][tj][r];
  } else {
    f32x4 a2[3];
#pragma unroll
    for (int t = 0; t < 3; t++) a2[t] = (f32x4){0.f, 0.f, 0.f, 0.f};
    for (int ks = 0; ks < 192; ks += 32) {
#pragma unroll
      for (int t = 0; t < 3; t++) {
        short8 afr = *(const short8*)&Hs[row0 + t * 16 + l15][ks + lg * 8];
        short8 bfr = load_cvt8(W1 + (size_t)(row0 + t * 16 + l15) * CDIM + ks + lg * 8);
        a2[t] = MFMA16(afr, bfr, a2[t]);
      }
    }
    float* dst = nqk + ((size_t)(type - 1) * NB + b) * CDIM;
#pragma unroll
    for (int t = 0; t < 3; t++)
#pragma unroll
      for (int r = 0; r < 4; r++)
        if (lg * 4 + r == l15) dst[row0 + t * 16 + l15] = a2[t][r];
  }
}

// ---------------- Kernel 2b: per-head softmax ----------------
__global__ void k2b(const float* __restrict__ A_pre, const float* __restrict__ nqk,
                    float* __restrict__ attnw) {
  const int b = blockIdx.x, tid = threadIdx.x;
  const int h = tid >> 5, r = tid & 31;
  if (r >= 24) return;
  const float* Ab = A_pre + (size_t)b * GSZ;
  const float* nq = nqk + (size_t)b * CDIM;
  const float* nk = nqk + (size_t)(NB + b) * CDIM;
  const int c = h * 24 + r;
  const float qn = rsqrtf(fmaxf(nq[c], 1e-24f));
  float e[24];
  float mx = -1e30f;
#pragma unroll
  for (int d = 0; d < 24; d++) {
    float kn = rsqrtf(fmaxf(nk[h * 24 + d], 1e-24f));
    float l = Ab[(size_t)c * CDIM + h * 24 + d] * qn * kn;
    e[d] = l;
    mx = fmaxf(mx, l);
  }
  float s = 0.f;
#pragma unroll
  for (int d = 0; d < 24; d++) {
    float x = __expf(e[d] - mx);
    e[d] = x;
    s += x;
  }
  const float inv = 1.0f / s;
  float* dst = attnw + (((size_t)b * NB + h) * 24 + r) * 24;
#pragma unroll
  for (int d = 0; d < 24; d++) dst[d] = e[d] * inv;
}

// ---------------- Kernel 3: P = Wo * blockdiag(attn) * Wv  (bf16 out) -------
__global__ __launch_bounds__(256) void k3(const float* __restrict__ attnw,
                                          const float* __restrict__ Wo,
                                          const unsigned short* __restrict__ WvT,
                                          unsigned short* __restrict__ Pbf) {
  const int b = blockIdx.x;
  __shared__ __align__(16) unsigned short AT[192][200];
  __shared__ __align__(16) unsigned short Ms[192][200];
  const int tid = threadIdx.x, wave = tid >> 6, lane = tid & 63;
  const int l15 = lane & 15, lg = lane >> 4, row0 = wave * 48;

  unsigned int* ATu = (unsigned int*)&AT[0][0];
  for (int i = tid; i < 192 * 100; i += 256) ATu[i] = 0u;
  __syncthreads();
  const float* at = attnw + (size_t)b * NB * 24 * 24;
  for (int i = tid; i < 4608; i += 256) {
    int h = i / 576, rem = i % 576, c = rem / 24, d = rem % 24;
    AT[h * 24 + d][h * 24 + c] = bf16u_rne(at[(h * 24 + c) * 24 + d]);
  }
  __syncthreads();

  f32x4 acc[3][12];
#pragma unroll
  for (int t = 0; t < 3; t++)
#pragma unroll
    for (int j = 0; j < 12; j++) acc[t][j] = (f32x4){0.f, 0.f, 0.f, 0.f};
  for (int ks = 0; ks < 192; ks += 32) {
    short8 afr[3];
#pragma unroll
    for (int t = 0; t < 3; t++)
      afr[t] = load_cvt8(Wo + (size_t)(row0 + t * 16 + l15) * CDIM + ks + lg * 8);
#pragma unroll
    for (int tj = 0; tj < 12; tj++) {
      short8 bfr = *(const short8*)&AT[tj * 16 + l15][ks + lg * 8];
#pragma unroll
      for (int t = 0; t < 3; t++) acc[t][tj] = MFMA16(afr[t], bfr, acc[t][tj]);
    }
  }
#pragma unroll
  for (int t = 0; t < 3; t++)
#pragma unroll
    for (int tj = 0; tj < 12; tj++)
#pragma unroll
      for (int r = 0; r < 4; r++)
        Ms[row0 + t * 16 + lg * 4 + r][tj * 16 + l15] = bf16u_rne(acc[t][tj][r]);
  __syncthreads();

  f32x4 a2[3][12];
#pragma unroll
  for (int t = 0; t < 3; t++)
#pragma unroll
    for (int j = 0; j < 12; j++) a2[t][j] = (f32x4){0.f, 0.f, 0.f, 0.f};
  for (int ks = 0; ks < 192; ks += 32) {
    short8 afr[3];
#pragma unroll
    for (int t = 0; t < 3; t++)
      afr[t] = *(const short8*)&Ms[row0 + t * 16 + l15][ks + lg * 8];
#pragma unroll
    for (int tj = 0; tj < 12; tj++) {
      short8 bfr = *(const short8*)(WvT + (size_t)(tj * 16 + l15) * CDIM + ks + lg * 8);
#pragma unroll
      for (int t = 0; t < 3; t++) a2[t][tj] = MFMA16(afr[t], bfr, a2[t][tj]);
    }
  }
  unsigned short* Pb = Pbf + (size_t)b * GSZ;
#pragma unroll
  for (int t = 0; t < 3; t++)
#pragma unroll
    for (int tj = 0; tj < 12; tj++)
#pragma unroll
      for (int r = 0; r < 4; r++)
        Pb[(size_t)(row0 + t * 16 + lg * 4 + r) * CDIM + tj * 16 + l15] = bf16u_rne(a2[t][tj][r]);
}

// ---------------- Kernel D: out = P @ input  ----------------
__global__ __launch_bounds__(256) void kD(const unsigned short* __restrict__ Pbf,
                                          const float* __restrict__ input,
                                          float* __restrict__ out) {
  const int nchunk = blockIdx.x, b = blockIdx.y;
  const int n0 = nchunk * 128;
  __shared__ __align__(16) char BsT[128 * 384];
  const int tid = threadIdx.x, wave = tid >> 6, lane = tid & 63;
  const int l15 = lane & 15, lg = lane >> 4, row0 = wave * 48;

  {
    const int n4 = (tid & 31) * 4;
    const int kb0 = (tid >> 5) * 4;
    const float* src = input + (size_t)b * CDIM * HW + n0 + n4;
    f32x4 w[24];
#pragma unroll
    for (int rnd = 0; rnd < 6; ++rnd)
#pragma unroll
      for (int j = 0; j < 4; ++j)
        w[rnd * 4 + j] = *(const f32x4*)(src + (size_t)(kb0 + rnd * 32 + j) * HW);
    __builtin_amdgcn_sched_barrier(0);
    char* bsb = BsT;
#pragma unroll
    for (int rnd = 0; rnd < 6; ++rnd) {
      const int kb = kb0 + rnd * 32;
#pragma unroll
      for (int i = 0; i < 4; ++i) {
        const int n = n4 + i;
        unsigned long long pk =
            (unsigned long long)pack_rne(w[rnd * 4 + 0][i], w[rnd * 4 + 1][i]) |
            ((unsigned long long)pack_rne(w[rnd * 4 + 2][i], w[rnd * 4 + 3][i]) << 32);
        *(unsigned long long*)(bsb + n * 384 + ((kb * 2) ^ ((n & 7) << 4))) = pk;
      }
    }
  }
  __syncthreads();

  f32x4 acc[3][8];
#pragma unroll
  for (int t = 0; t < 3; t++)
#pragma unroll
    for (int j = 0; j < 8; j++) acc[t][j] = (f32x4){0.f, 0.f, 0.f, 0.f};

  const unsigned short* Pb = Pbf + (size_t)b * GSZ;
#pragma unroll 2
  for (int ks = 0; ks < 6; ks++) {
    short8 afr[3];
#pragma unroll
    for (int t = 0; t < 3; t++)
      afr[t] = *(const short8*)(Pb + (size_t)(row0 + t * 16 + l15) * CDIM + ks * 32 + lg * 8);
#pragma unroll
    for (int tn = 0; tn < 8; tn++) {
      const int n = tn * 16 + l15;
      short8 bfr = *(const short8*)(BsT + n * 384 + ((ks * 64 + lg * 16) ^ ((n & 7) << 4)));
#pragma unroll
      for (int t = 0; t < 3; t++) acc[t][tn] = MFMA16(afr[t], bfr, acc[t][tn]);
    }
  }
  float* ob = out + (size_t)b * CDIM * HW + n0;
#pragma unroll
  for (int t = 0; t < 3; t++)
#pragma unroll
    for (int tn = 0; tn < 8; tn++)
#pragma unroll
      for (int r = 0; r < 4; r++) {
        const int m = row0 + t * 16 + lg * 4 + r;
        ob[(size_t)m * HW + tn * 16 + l15] = acc[t][tn][r];
      }
}

// ---------------- launch ----------------
extern "C" void kernel_launch(void* const* d_in, const int* in_sizes, int n_in,
                              void* d_out, int out_size, void* d_ws, size_t ws_size,
                              hipStream_t stream) {
  const float* input = (const float*)d_in[0];
  const float* color = (const float*)d_in[1];
  const float* Wq = (const float*)d_in[2];
  const float* Wk = (const float*)d_in[3];
  const float* Wv = (const float*)d_in[4];
  const float* Wo = (const float*)d_in[5];
  float* out = (float*)d_out;
  char* ws = (char*)d_ws;

  const size_t OFF_G = 0;                        // 3*8*192*192*4 = 3538944
  const size_t OFF_APRE = 3538944;               // 8*192*192*4  = 1179648
  const size_t OFF_NQK = OFF_APRE + 1179648;     // 2*8*192*4    = 12288
  const size_t OFF_ATT = OFF_NQK + 12288;        // 8*8*24*24*4  = 147456
  const size_t OFF_WVT = OFF_ATT + 147456;       // 192*192*2    = 73728
  const size_t OFF_PBF = OFF_WVT + 73728;        // 8*192*192*2  = 589824

  float* G = (float*)(ws + OFF_G);
  float* A_pre = (float*)(ws + OFF_APRE);
  float* nqk = (float*)(ws + OFF_NQK);
  float* attnw = (float*)(ws + OFF_ATT);
  unsigned short* WvT = (unsigned short*)(ws + OFF_WVT);
  unsigned short* Pbf = (unsigned short*)(ws + OFF_PBF);

  // Partials (bf16 blocked records) live in d_out as scratch:
  // 64*8*78*2048 = 81,788,928 B <= out_size*4 = 100,663,296 B.
  // kD overwrites d_out last; reduce_k consumes partials before that.
  unsigned long long* part = (unsigned long long*)d_out;

  k0_wvt<<<dim3(144), dim3(256), 0, stream>>>(Wv, WvT);
  gram2_k<<<dim3(NPART, NB), dim3(768), 0, stream>>>(input, color, part);
  reduce_k<NPART><<<dim3(NREC, NB), dim3(256), 0, stream>>>(part, G);
  k2a<<<dim3(NB, 3), dim3(256), 0, stream>>>(G, Wq, Wk, A_pre, nqk);
  k2b<<<dim3(NB), dim3(256), 0, stream>>>(A_pre, nqk, attnw);
  k3<<<dim3(NB), dim3(256), 0, stream>>>(attnw, Wo, WvT, Pbf);
  kD<<<dim3(HW / 128, NB), dim3(256), 0, stream>>>(Pbf, input, out);
}

// Round 19
// 180.964 us; speedup vs baseline: 1.1324x; 1.1324x over previous
//
#include <hip/hip_runtime.h>
#include <hip/hip_bf16.h>

// Color_Attention: transposed (channel) attention.
//   gram2_k (fused): 768 thr / 12 waves. Staging now bypasses global_load_lds
//   (every gload_lds variant plateaued at ~8.9 GB/s/CU): per-lane f32x4 loads
//   -> in-register bf16 pack -> ds_write_b128 into bbuf (80B rows). Loads for
//   pair cp+1 are issued before the MFMA of pair cp (fly under compute).
//   LDS = bbuf only (31KB). Sync via __syncthreads() (R13 raw-barrier raced).
//   MFMA 32x32x16 on Z*Z^T upper triangle: 6 pairs (r,11-r) x 13 tiles split
//   7/6 across two waves (acc 112 AGPR; no launch_bounds mins - R14 lesson).
//   Partials bf16 blocked 2KB records in d_out scratch (NPART=32, 41MB);
//   reduce_k<32> sums -> fp32 G (both triangles, verified 32x32 C/D layout).
//   A_pre = Wq*G_ci*Wk^T ; nq = diag(Wq*G_cc*Wq^T); nk = diag(Wk*G_ii*Wk^T)
//   attn = softmax over head-diagonal 24x24 blocks of A_pre/(nq*nk)
//   P = Wo * blockdiag(attn) * Wv ; out = P @ input

typedef __attribute__((ext_vector_type(4))) float f32x4;
typedef __attribute__((ext_vector_type(16))) float f32x16;
typedef __attribute__((ext_vector_type(8))) short short8;

#define MFMA16(a, b, c) __builtin_amdgcn_mfma_f32_16x16x32_bf16((a), (b), (c), 0, 0, 0)
#define MFMA32(a, b, c) __builtin_amdgcn_mfma_f32_32x32x16_bf16((a), (b), (c), 0, 0, 0)

__device__ __forceinline__ unsigned int pack_rne(float a, float b) {
  unsigned int ua = __float_as_uint(a), ub = __float_as_uint(b);
  ua += 0x7fffu + ((ua >> 16) & 1u);
  ub += 0x7fffu + ((ub >> 16) & 1u);
  return (ua >> 16) | (ub & 0xffff0000u);
}
__device__ __forceinline__ unsigned short bf16u_rne(float x) {
  unsigned int u = __float_as_uint(x);
  u += 0x7fffu + ((u >> 16) & 1u);
  return (unsigned short)(u >> 16);
}
union S8U { short8 s; unsigned int u[4]; };
__device__ __forceinline__ short8 load_cvt8(const float* p) {
  f32x4 x = *(const f32x4*)p;
  f32x4 y = *(const f32x4*)(p + 4);
  S8U r;
  r.u[0] = pack_rne(x[0], x[1]);
  r.u[1] = pack_rne(x[2], x[3]);
  r.u[2] = pack_rne(y[0], y[1]);
  r.u[3] = pack_rne(y[2], y[3]);
  return r.s;
}

#define HW 16384
#define CDIM 192
#define NB 8
#define GSZ (CDIM * CDIM)
#define NREC 78       // 32x32 upper-triangle tiles of the 384x384 gram
#define NPART 32      // partial sets (grid.x); 256 blocks
#define NCP 16        // chunk-pairs (32 cols) per block: 32*16*32 = 16384
#define BROW 80       // bf16 buffer row stride

// ---------------- Kernel 0: transpose Wv -> bf16 WvT ----------------
__global__ void k0_wvt(const float* __restrict__ Wv, unsigned short* __restrict__ WvT) {
  int idx = blockIdx.x * 256 + threadIdx.x;
  if (idx < CDIM * CDIM) {
    int j = idx / CDIM, cp = idx % CDIM;
    WvT[idx] = bf16u_rne(Wv[(size_t)cp * CDIM + j]);
  }
}

// ---------------- Kernel B (fused): gram Z*Z^T, register staging -------------
// Pair p owns 32-row-tiles {p, 11-p}: 13 upper-triangle tiles
//   i=0..(11-p): rt=p, ct=p+i;  i=(12-p)..12: rt=11-p, ct=i-(12-p)+(11-p)
// HALF 0 -> i=0..6 (7 tiles), HALF 1 -> i=7..12 (6 tiles).
template <int P, int H>
__device__ __forceinline__ void pair_step32(const char* bb, f32x16* acc,
                                            int l31, int hi16, int kb) {
  constexpr int N0 = 12 - P;
  constexpr int I0 = H ? 7 : 0;
  constexpr int I1 = H ? 13 : 7;
  const short8 aP = *(const short8*)(bb + (P * 32 + l31) * BROW + hi16 + kb);
  short8 aQ = aP;
  if constexpr (I1 > N0)
    aQ = *(const short8*)(bb + ((11 - P) * 32 + l31) * BROW + hi16 + kb);
#pragma unroll
  for (int i = I0; i < I1; ++i) {
    const int ct = (i < N0) ? (P + i) : (i - N0 + 11 - P);
    const short8 bfr = *(const short8*)(bb + (ct * 32 + l31) * BROW + hi16 + kb);
    acc[i - I0] = MFMA32((i < N0) ? aP : aQ, bfr, acc[i - I0]);
  }
}

template <int P, int H>
__device__ __forceinline__ void pair_both(const char* bb, f32x16* acc,
                                          int l31, int hi16) {
  pair_step32<P, H>(bb, acc, l31, hi16, 0);
  pair_step32<P, H>(bb, acc, l31, hi16, 32);
}

__device__ __forceinline__ void pair_dispatch(int wave, const char* bb,
                                              f32x16* acc, int l31, int hi16) {
  switch (wave) {
    case 0: pair_both<0, 0>(bb, acc, l31, hi16); break;
    case 1: pair_both<0, 1>(bb, acc, l31, hi16); break;
    case 2: pair_both<1, 0>(bb, acc, l31, hi16); break;
    case 3: pair_both<1, 1>(bb, acc, l31, hi16); break;
    case 4: pair_both<2, 0>(bb, acc, l31, hi16); break;
    case 5: pair_both<2, 1>(bb, acc, l31, hi16); break;
    case 6: pair_both<3, 0>(bb, acc, l31, hi16); break;
    case 7: pair_both<3, 1>(bb, acc, l31, hi16); break;
    case 8: pair_both<4, 0>(bb, acc, l31, hi16); break;
    case 9: pair_both<4, 1>(bb, acc, l31, hi16); break;
    case 10: pair_both<5, 0>(bb, acc, l31, hi16); break;
    default: pair_both<5, 1>(bb, acc, l31, hi16); break;
  }
}

// grid (NPART, 8), 768 threads (12 waves). LDS = bbuf 30KB only.
// Thread owns 2 staging units of 32B per pair: unit0 = input row (tid>>2),
// unit1 = color row (tid>>2); sub = tid&3 selects 8-float piece of the
// 32-col pair span. bbuf row = 32 contiguous bf16 cols (pair), 80B stride.
// Schedule per pair cp:
//   sync A (bbuf free) -> pack regs -> ds_write -> sync B (bbuf ready)
//   -> issue loads for pair cp+1 (fly under MFMA) -> MFMA on bbuf.
__global__ __launch_bounds__(768) void gram2_k(const float* __restrict__ input,
                                               const float* __restrict__ color,
                                               unsigned long long* __restrict__ part) {
  __shared__ __align__(16) char bbuf[384 * BROW];
  const int tid = threadIdx.x, wave = tid >> 6, lane = tid & 63;
  const int l31 = lane & 31, hi16 = (lane >> 5) * 16;
  const int strip = blockIdx.x, b = blockIdx.y;
  const int row = tid >> 2, sub = tid & 3;
  const float* ip = input + (size_t)b * CDIM * HW + (size_t)row * HW;
  const float* cp_ = color + (size_t)b * CDIM * HW + (size_t)row * HW;
  const int ch0 = strip * NCP * 2;  // base chunk (16-col units)

  f32x16 acc[7];
#pragma unroll
  for (int s = 0; s < 7; ++s)
#pragma unroll
    for (int c = 0; c < 16; ++c) acc[s][c] = 0.f;

  // per-pair column base (floats) for this thread's piece
  // colf(cp) = (ch0 + 2*cp + (sub>>1))*16 + (sub&1)*8
  f32x4 vi0, vi1, vc0, vc1;
  {
    const int colf = (ch0 + (sub >> 1)) * 16 + (sub & 1) * 8;
    vi0 = *(const f32x4*)(ip + colf);
    vi1 = *(const f32x4*)(ip + colf + 4);
    vc0 = *(const f32x4*)(cp_ + colf);
    vc1 = *(const f32x4*)(cp_ + colf + 4);
  }

#pragma unroll 1
  for (int cpi = 0; cpi < NCP; ++cpi) {
    __syncthreads();  // A: bbuf free (all waves done with prior MFMA)
    {
      S8U pk;
      pk.u[0] = pack_rne(vi0[0], vi0[1]);
      pk.u[1] = pack_rne(vi0[2], vi0[3]);
      pk.u[2] = pack_rne(vi1[0], vi1[1]);
      pk.u[3] = pack_rne(vi1[2], vi1[3]);
      *(short8*)(bbuf + row * BROW + sub * 16) = pk.s;
      pk.u[0] = pack_rne(vc0[0], vc0[1]);
      pk.u[1] = pack_rne(vc0[2], vc0[3]);
      pk.u[2] = pack_rne(vc1[0], vc1[1]);
      pk.u[3] = pack_rne(vc1[2], vc1[3]);
      *(short8*)(bbuf + (192 + row) * BROW + sub * 16) = pk.s;
    }
    __syncthreads();  // B: bbuf visible
    if (cpi + 1 < NCP) {
      const int colf = (ch0 + 2 * (cpi + 1) + (sub >> 1)) * 16 + (sub & 1) * 8;
      vi0 = *(const f32x4*)(ip + colf);
      vi1 = *(const f32x4*)(ip + colf + 4);
      vc0 = *(const f32x4*)(cp_ + colf);
      vc1 = *(const f32x4*)(cp_ + colf + 4);
    }
    pair_dispatch(wave, bbuf, acc, l31, hi16);
  }

  // ---- blocked flush, bf16: one contiguous 2KB record per 32x32 tile ----
  unsigned long long* pbase = part + (size_t)(b * NPART + strip) * NREC * 256;
  const int p = wave >> 1, H = wave & 1;
  const int Rbase = p * 13 + (H ? 7 : 0);
  const int NT = H ? 6 : 7;
#pragma unroll
  for (int s = 0; s < 7; ++s) {
    if (s < NT) {
#pragma unroll
      for (int j = 0; j < 4; ++j) {
        const unsigned long long pk =
            (unsigned long long)pack_rne(acc[s][4 * j], acc[s][4 * j + 1]) |
            ((unsigned long long)pack_rne(acc[s][4 * j + 2], acc[s][4 * j + 3]) << 32);
        pbase[((size_t)(Rbase + s) * 4 + j) * 64 + lane] = pk;
      }
    }
  }
}

// ---------------- reduce blocked bf16 partials -> fp32 G (both triangles) ---
// grid (78, NB), 256 threads: one 32x32 record per block, NP fully unrolled.
template <int NP>
__global__ __launch_bounds__(256) void reduce_k(const unsigned long long* __restrict__ part,
                                                float* __restrict__ G) {
  const int b = blockIdx.y, T = blockIdx.x;
  const int j = threadIdx.x >> 6, lane = threadIdx.x & 63;
  const unsigned long long* p0 =
      part + ((size_t)b * NP * NREC + T) * 256 + j * 64 + lane;
  float s0 = 0.f, s1 = 0.f, s2 = 0.f, s3 = 0.f;
#pragma unroll
  for (int s = 0; s < NP; ++s) {
    const unsigned long long v = p0[(size_t)s * NREC * 256];
    const unsigned int lo = (unsigned int)v, hi = (unsigned int)(v >> 32);
    s0 += __uint_as_float(lo << 16);
    s1 += __uint_as_float(lo & 0xffff0000u);
    s2 += __uint_as_float(hi << 16);
    s3 += __uint_as_float(hi & 0xffff0000u);
  }
  // decode record T -> 32-tile (rt, ct), rt <= ct
  const int p = T / 13, i = T % 13;
  const int N0 = 12 - p;
  const int rt = (i < N0) ? p : 11 - p;
  const int ct = (i < N0) ? p + i : i - N0 + 11 - p;
  const int hi5 = lane >> 5, col = lane & 31;
  const int zc = ct * 32 + col;
  const float sums[4] = {s0, s1, s2, s3};
#pragma unroll
  for (int m = 0; m < 4; ++m) {
    const int zr = rt * 32 + m + 8 * j + 4 * hi5;
    int type, gr, gc;
    if (zc < 192) { type = 2; gr = zr; gc = zc; }            // I*I^T
    else if (zr < 192) { type = 0; gr = zr; gc = zc - 192; } // I*C^T (full)
    else { type = 1; gr = zr - 192; gc = zc - 192; }         // C*C^T
    float* Gm = G + ((size_t)type * NB + b) * GSZ;
    Gm[(size_t)gr * CDIM + gc] = sums[m];
    if (type != 0 && rt != ct) Gm[(size_t)gc * CDIM + gr] = sums[m];
  }
}

// ---------------- Kernel 2a: A_pre (type0), nq (type1), nk (type2) ----------
__global__ __launch_bounds__(256) void k2a(const float* __restrict__ G,
                                           const float* __restrict__ Wq,
                                           const float* __restrict__ Wk,
                                           float* __restrict__ A_pre,
                                           float* __restrict__ nqk) {
  const int b = blockIdx.x, type = blockIdx.y;
  __shared__ __align__(16) unsigned short Hs[192][200];
  const int tid = threadIdx.x, wave = tid >> 6, lane = tid & 63;
  const int l15 = lane & 15, lg = lane >> 4, row0 = wave * 48;
  const float* W1 = (type == 2) ? Wk : Wq;
  const float* Gm = G + ((size_t)type * NB + b) * GSZ;

  f32x4 acc[3][12];
#pragma unroll
  for (int t = 0; t < 3; t++)
#pragma unroll
    for (int j = 0; j < 12; j++) acc[t][j] = (f32x4){0.f, 0.f, 0.f, 0.f};

  for (int ks = 0; ks < 192; ks += 32) {
    short8 afr[3];
#pragma unroll
    for (int t = 0; t < 3; t++)
      afr[t] = load_cvt8(W1 + (size_t)(row0 + t * 16 + l15) * CDIM + ks + lg * 8);
#pragma unroll
    for (int tj = 0; tj < 12; tj++) {
      short8 bfr = load_cvt8(Gm + (size_t)(tj * 16 + l15) * CDIM + ks + lg * 8);
#pragma unroll
      for (int t = 0; t < 3; t++) acc[t][tj] = MFMA16(afr[t], bfr, acc[t][tj]);
    }
  }
#pragma unroll
  for (int t = 0; t < 3; t++)
#pragma unroll
    for (int tj = 0; tj < 12; tj++)
#pragma unroll
      for (int r = 0; r < 4; r++)
        Hs[row0 + t * 16 + lg * 4 + r][tj * 16 + l15] = bf16u_rne(acc[t][tj][r]);
  __syncthreads();

  if (type == 0) {
    f32x4 a2[3][12];
#pragma unroll
    for (int t = 0; t < 3; t++)
#pragma unroll
      for (int j = 0; j < 12; j++) a2[t][j] = (f32x4){0.f, 0.f, 0.f, 0.f};
    for (int ks = 0; ks < 192; ks += 32) {
      short8 afr[3];
#pragma unroll
      for (int t = 0; t < 3; t++)
        afr[t] = *(const short8*)&Hs[row0 + t * 16 + l15][ks + lg * 8];
#pragma unroll
      for (int tj = 0; tj < 12; tj++) {
        short8 bfr = load_cvt8(Wk + (size_t)(tj * 16 + l15) * CDIM + ks + lg * 8);
#pragma unroll
        for (int t = 0; t < 3; t++) a2[t][tj] = MFMA16(afr[t], bfr, a2[t][tj]);
      }
    }
    float* Ab = A_pre + (size_t)b * GSZ;
#pragma unroll
    for (int t = 0; t < 3; t++)
#pragma unroll
      for (int tj = 0; tj < 12; tj++)
#pragma unroll
        for (int r = 0; r < 4; r++)
          Ab[(size_t)(row0 + t * 16 + lg * 4 + r) * CDIM + tj * 16 + l15] = a2[t][tj][r];
  } else {
    f32x4 a2[3];
#pragma unroll
    for (int t = 0; t < 3; t++) a2[t] = (f32x4){0.f, 0.f, 0.f, 0.f};
    for (int ks = 0; ks < 192; ks += 32) {
#pragma unroll
      for (int t = 0; t < 3; t++) {
        short8 afr = *(const short8*)&Hs[row0 + t * 16 + l15][ks + lg * 8];
        short8 bfr = load_cvt8(W1 + (size_t)(row0 + t * 16 + l15) * CDIM + ks + lg * 8);
        a2[t] = MFMA16(afr, bfr, a2[t]);
      }
    }
    float* dst = nqk + ((size_t)(type - 1) * NB + b) * CDIM;
#pragma unroll
    for (int t = 0; t < 3; t++)
#pragma unroll
      for (int r = 0; r < 4; r++)
        if (lg * 4 + r == l15) dst[row0 + t * 16 + l15] = a2[t][r];
  }
}

// ---------------- Kernel 2b: per-head softmax ----------------
__global__ void k2b(const float* __restrict__ A_pre, const float* __restrict__ nqk,
                    float* __restrict__ attnw) {
  const int b = blockIdx.x, tid = threadIdx.x;
  const int h = tid >> 5, r = tid & 31;
  if (r >= 24) return;
  const float* Ab = A_pre + (size_t)b * GSZ;
  const float* nq = nqk + (size_t)b * CDIM;
  const float* nk = nqk + (size_t)(NB + b) * CDIM;
  const int c = h * 24 + r;
  const float qn = rsqrtf(fmaxf(nq[c], 1e-24f));
  float e[24];
  float mx = -1e30f;
#pragma unroll
  for (int d = 0; d < 24; d++) {
    float kn = rsqrtf(fmaxf(nk[h * 24 + d], 1e-24f));
    float l = Ab[(size_t)c * CDIM + h * 24 + d] * qn * kn;
    e[d] = l;
    mx = fmaxf(mx, l);
  }
  float s = 0.f;
#pragma unroll
  for (int d = 0; d < 24; d++) {
    float x = __expf(e[d] - mx);
    e[d] = x;
    s += x;
  }
  const float inv = 1.0f / s;
  float* dst = attnw + (((size_t)b * NB + h) * 24 + r) * 24;
#pragma unroll
  for (int d = 0; d < 24; d++) dst[d] = e[d] * inv;
}

// ---------------- Kernel 3: P = Wo * blockdiag(attn) * Wv  (bf16 out) -------
__global__ __launch_bounds__(256) void k3(const float* __restrict__ attnw,
                                          const float* __restrict__ Wo,
                                          const unsigned short* __restrict__ WvT,
                                          unsigned short* __restrict__ Pbf) {
  const int b = blockIdx.x;
  __shared__ __align__(16) unsigned short AT[192][200];
  __shared__ __align__(16) unsigned short Ms[192][200];
  const int tid = threadIdx.x, wave = tid >> 6, lane = tid & 63;
  const int l15 = lane & 15, lg = lane >> 4, row0 = wave * 48;

  unsigned int* ATu = (unsigned int*)&AT[0][0];
  for (int i = tid; i < 192 * 100; i += 256) ATu[i] = 0u;
  __syncthreads();
  const float* at = attnw + (size_t)b * NB * 24 * 24;
  for (int i = tid; i < 4608; i += 256) {
    int h = i / 576, rem = i % 576, c = rem / 24, d = rem % 24;
    AT[h * 24 + d][h * 24 + c] = bf16u_rne(at[(h * 24 + c) * 24 + d]);
  }
  __syncthreads();

  f32x4 acc[3][12];
#pragma unroll
  for (int t = 0; t < 3; t++)
#pragma unroll
    for (int j = 0; j < 12; j++) acc[t][j] = (f32x4){0.f, 0.f, 0.f, 0.f};
  for (int ks = 0; ks < 192; ks += 32) {
    short8 afr[3];
#pragma unroll
    for (int t = 0; t < 3; t++)
      afr[t] = load_cvt8(Wo + (size_t)(row0 + t * 16 + l15) * CDIM + ks + lg * 8);
#pragma unroll
    for (int tj = 0; tj < 12; tj++) {
      short8 bfr = *(const short8*)&AT[tj * 16 + l15][ks + lg * 8];
#pragma unroll
      for (int t = 0; t < 3; t++) acc[t][tj] = MFMA16(afr[t], bfr, acc[t][tj]);
    }
  }
#pragma unroll
  for (int t = 0; t < 3; t++)
#pragma unroll
    for (int tj = 0; tj < 12; tj++)
#pragma unroll
      for (int r = 0; r < 4; r++)
        Ms[row0 + t * 16 + lg * 4 + r][tj * 16 + l15] = bf16u_rne(acc[t][tj][r]);
  __syncthreads();

  f32x4 a2[3][12];
#pragma unroll
  for (int t = 0; t < 3; t++)
#pragma unroll
    for (int j = 0; j < 12; j++) a2[t][j] = (f32x4){0.f, 0.f, 0.f, 0.f};
  for (int ks = 0; ks < 192; ks += 32) {
    short8 afr[3];
#pragma unroll
    for (int t = 0; t < 3; t++)
      afr[t] = *(const short8*)&Ms[row0 + t * 16 + l15][ks + lg * 8];
#pragma unroll
    for (int tj = 0; tj < 12; tj++) {
      short8 bfr = *(const short8*)(WvT + (size_t)(tj * 16 + l15) * CDIM + ks + lg * 8);
#pragma unroll
      for (int t = 0; t < 3; t++) a2[t][tj] = MFMA16(afr[t], bfr, a2[t][tj]);
    }
  }
  unsigned short* Pb = Pbf + (size_t)b * GSZ;
#pragma unroll
  for (int t = 0; t < 3; t++)
#pragma unroll
    for (int tj = 0; tj < 12; tj++)
#pragma unroll
      for (int r = 0; r < 4; r++)
        Pb[(size_t)(row0 + t * 16 + lg * 4 + r) * CDIM + tj * 16 + l15] = bf16u_rne(a2[t][tj][r]);
}

// ---------------- Kernel D: out = P @ input  ----------------
__global__ __launch_bounds__(256) void kD(const unsigned short* __restrict__ Pbf,
                                          const float* __restrict__ input,
                                          float* __restrict__ out) {
  const int nchunk = blockIdx.x, b = blockIdx.y;
  const int n0 = nchunk * 128;
  __shared__ __align__(16) char BsT[128 * 384];
  const int tid = threadIdx.x, wave = tid >> 6, lane = tid & 63;
  const int l15 = lane & 15, lg = lane >> 4, row0 = wave * 48;

  {
    const int n4 = (tid & 31) * 4;
    const int kb0 = (tid >> 5) * 4;
    const float* src = input + (size_t)b * CDIM * HW + n0 + n4;
    f32x4 w[24];
#pragma unroll
    for (int rnd = 0; rnd < 6; ++rnd)
#pragma unroll
      for (int j = 0; j < 4; ++j)
        w[rnd * 4 + j] = *(const f32x4*)(src + (size_t)(kb0 + rnd * 32 + j) * HW);
    __builtin_amdgcn_sched_barrier(0);
    char* bsb = BsT;
#pragma unroll
    for (int rnd = 0; rnd < 6; ++rnd) {
      const int kb = kb0 + rnd * 32;
#pragma unroll
      for (int i = 0; i < 4; ++i) {
        const int n = n4 + i;
        unsigned long long pk =
            (unsigned long long)pack_rne(w[rnd * 4 + 0][i], w[rnd * 4 + 1][i]) |
            ((unsigned long long)pack_rne(w[rnd * 4 + 2][i], w[rnd * 4 + 3][i]) << 32);
        *(unsigned long long*)(bsb + n * 384 + ((kb * 2) ^ ((n & 7) << 4))) = pk;
      }
    }
  }
  __syncthreads();

  f32x4 acc[3][8];
#pragma unroll
  for (int t = 0; t < 3; t++)
#pragma unroll
    for (int j = 0; j < 8; j++) acc[t][j] = (f32x4){0.f, 0.f, 0.f, 0.f};

  const unsigned short* Pb = Pbf + (size_t)b * GSZ;
#pragma unroll 2
  for (int ks = 0; ks < 6; ks++) {
    short8 afr[3];
#pragma unroll
    for (int t = 0; t < 3; t++)
      afr[t] = *(const short8*)(Pb + (size_t)(row0 + t * 16 + l15) * CDIM + ks * 32 + lg * 8);
#pragma unroll
    for (int tn = 0; tn < 8; tn++) {
      const int n = tn * 16 + l15;
      short8 bfr = *(const short8*)(BsT + n * 384 + ((ks * 64 + lg * 16) ^ ((n & 7) << 4)));
#pragma unroll
      for (int t = 0; t < 3; t++) acc[t][tn] = MFMA16(afr[t], bfr, acc[t][tn]);
    }
  }
  float* ob = out + (size_t)b * CDIM * HW + n0;
#pragma unroll
  for (int t = 0; t < 3; t++)
#pragma unroll
    for (int tn = 0; tn < 8; tn++)
#pragma unroll
      for (int r = 0; r < 4; r++) {
        const int m = row0 + t * 16 + lg * 4 + r;
        ob[(size_t)m * HW + tn * 16 + l15] = acc[t][tn][r];
      }
}

// ---------------- launch ----------------
extern "C" void kernel_launch(void* const* d_in, const int* in_sizes, int n_in,
                              void* d_out, int out_size, void* d_ws, size_t ws_size,
                              hipStream_t stream) {
  const float* input = (const float*)d_in[0];
  const float* color = (const float*)d_in[1];
  const float* Wq = (const float*)d_in[2];
  const float* Wk = (const float*)d_in[3];
  const float* Wv = (const float*)d_in[4];
  const float* Wo = (const float*)d_in[5];
  float* out = (float*)d_out;
  char* ws = (char*)d_ws;

  const size_t OFF_G = 0;                        // 3*8*192*192*4 = 3538944
  const size_t OFF_APRE = 3538944;               // 8*192*192*4  = 1179648
  const size_t OFF_NQK = OFF_APRE + 1179648;     // 2*8*192*4    = 12288
  const size_t OFF_ATT = OFF_NQK + 12288;        // 8*8*24*24*4  = 147456
  const size_t OFF_WVT = OFF_ATT + 147456;       // 192*192*2    = 73728
  const size_t OFF_PBF = OFF_WVT + 73728;        // 8*192*192*2  = 589824

  float* G = (float*)(ws + OFF_G);
  float* A_pre = (float*)(ws + OFF_APRE);
  float* nqk = (float*)(ws + OFF_NQK);
  float* attnw = (float*)(ws + OFF_ATT);
  unsigned short* WvT = (unsigned short*)(ws + OFF_WVT);
  unsigned short* Pbf = (unsigned short*)(ws + OFF_PBF);

  // Partials (bf16 blocked records) in d_out scratch:
  // 32*8*78*2048 = 40,894,464 B <= out_size*4 = 100,663,296 B.
  // reduce_k consumes them before kD overwrites d_out.
  unsigned long long* part = (unsigned long long*)d_out;

  k0_wvt<<<dim3(144), dim3(256), 0, stream>>>(Wv, WvT);
  gram2_k<<<dim3(NPART, NB), dim3(768), 0, stream>>>(input, color, part);
  reduce_k<NPART><<<dim3(NREC, NB), dim3(256), 0, stream>>>(part, G);
  k2a<<<dim3(NB, 3), dim3(256), 0, stream>>>(G, Wq, Wk, A_pre, nqk);
  k2b<<<dim3(NB), dim3(256), 0, stream>>>(A_pre, nqk, attnw);
  k3<<<dim3(NB), dim3(256), 0, stream>>>(attnw, Wo, WvT, Pbf);
  kD<<<dim3(HW / 128, NB), dim3(256), 0, stream>>>(Pbf, input, out);
}